// Round 1
// baseline (938.227 us; speedup 1.0000x reference)
//
#include <hip/hip_runtime.h>

// BitMoE: dense 8-expert BitNet MoE, T=4096 tokens, D=1024, H=4096.
// Round 5: both i8 GEMMs rebuilt as 256x256-tile, BK=64, 512-thread/8-wave,
// QUAD-buffered LDS (128 KiB) with counted s_waitcnt vmcnt(8) (T3+T4: loads
// stay in flight across barriers; never vmcnt(0) in the main loop), setprio
// around the MFMA cluster (T5), and expert->XCD blockIdx mapping (T1) so each
// XCD's L2 holds its expert's weight panel. Swizzle ck^=(row>>1)&3 keeps
// ds_read_b128 conflict-free at 64B rows. Numerics unchanged (exact i8 MFMA).

#define T_TOK 4096
#define DIMS  1024
#define HID   4096
#define NE    8
#define ROWB  8192ull   // byte stride of an h/qa row (4096 f16; i8 uses first 4096 B)

typedef __attribute__((ext_vector_type(4))) int       i32x4;
typedef __attribute__((ext_vector_type(8))) _Float16  f16x8;

// ---------- helpers ----------
__device__ __forceinline__ float block_sum(float v, float* buf, int tid) {
  #pragma unroll
  for (int o = 32; o > 0; o >>= 1) v += __shfl_down(v, o, 64);
  __syncthreads();
  if ((tid & 63) == 0) buf[tid >> 6] = v;
  __syncthreads();
  return buf[0] + buf[1] + buf[2] + buf[3];
}
__device__ __forceinline__ float block_max(float v, float* buf, int tid) {
  #pragma unroll
  for (int o = 32; o > 0; o >>= 1) { float t = __shfl_down(v, o, 64); v = fmaxf(v, t); }
  __syncthreads();
  if ((tid & 63) == 0) buf[tid >> 6] = v;
  __syncthreads();
  return fmaxf(fmaxf(buf[0], buf[1]), fmaxf(buf[2], buf[3]));
}

// async global->LDS, 16B per lane; LDS dest = wave-uniform base + lane*16
__device__ __forceinline__ void gl_lds16(const void* g, void* l) {
  __builtin_amdgcn_global_load_lds(
      (const __attribute__((address_space(1))) unsigned int*)g,
      (__attribute__((address_space(3))) unsigned int*)l, 16, 0, 0);
}

__device__ __forceinline__ int q8(float v) {
  return ((int)fminf(fmaxf(rintf(v), -128.0f), 127.0f)) & 0xff;
}

// branch-free erf, Abramowitz-Stegun 7.1.26
__device__ __forceinline__ float erf_fast(float x) {
  const float ax = fabsf(x);
  const float t = __builtin_amdgcn_rcpf(fmaf(0.3275911f, ax, 1.0f));
  float p = fmaf(1.061405429f, t, -1.453152027f);
  p = fmaf(p, t, 1.421413741f);
  p = fmaf(p, t, -0.284496736f);
  p = fmaf(p, t, 0.254829592f);
  p = p * t;
  const float e = __expf(-ax * ax);
  const float r = fmaf(-p, e, 1.0f);
  return copysignf(r, x);
}
__device__ __forceinline__ float gelu_fast(float h) {
  return 0.5f * h * (1.0f + erf_fast(h * 0.70710678118654752f));
}

// ---------- weight scale reduction: sum |w| per group ----------
__global__ __launch_bounds__(256) void wabs_sum_kernel(
    const float4* __restrict__ w, int n_f4, int shift, float* __restrict__ sums) {
  __shared__ float buf[4];
  const int tid = threadIdx.x;
  const int base = blockIdx.x * 4096;
  float acc = 0.0f;
  for (int k = 0; k < 16; ++k) {
    int fi = base + k * 256 + tid;
    if (fi < n_f4) {
      float4 v = w[fi];
      acc += fabsf(v.x) + fabsf(v.y) + fabsf(v.z) + fabsf(v.w);
    }
  }
  acc = block_sum(acc, buf, tid);
  if (tid == 0) atomicAdd(&sums[base >> shift], acc);
}

// ---------- scales ----------
__global__ void mkscales_kernel(const float* __restrict__ wsum, float* __restrict__ sc) {
  if (threadIdx.x == 0) {
    #pragma unroll
    for (int e = 0; e < NE; ++e) {
      float m1 = fmaxf(wsum[e] * (1.0f / 4194304.0f), 1e-5f);
      sc[e] = m1; sc[8 + e] = 1.0f / m1;
      float m2 = fmaxf(wsum[8 + e] * (1.0f / 4194304.0f), 1e-5f);
      sc[16 + e] = m2; sc[24 + e] = 1.0f / m2;
    }
    float mg = fmaxf(wsum[16] * (1.0f / 8192.0f), 1e-5f);
    sc[32] = mg; sc[33] = 1.0f / mg;
  }
}

// ---------- ternary weight quant -> i8 {-1,0,1} ----------
__global__ __launch_bounds__(256) void wquant_kernel(
    const float4* __restrict__ w, int* __restrict__ o, int n_f4, int shift,
    const float* __restrict__ qs) {
  int fi = blockIdx.x * 256 + threadIdx.x;
  if (fi >= n_f4) return;
  const float s = qs[fi >> shift];
  float4 v = w[fi];
  int b0 = ((int)fminf(fmaxf(rintf(v.x * s), -1.0f), 1.0f)) & 0xff;
  int b1 = ((int)fminf(fmaxf(rintf(v.y * s), -1.0f), 1.0f)) & 0xff;
  int b2 = ((int)fminf(fmaxf(rintf(v.z * s), -1.0f), 1.0f)) & 0xff;
  int b3 = ((int)fminf(fmaxf(rintf(v.w * s), -1.0f), 1.0f)) & 0xff;
  o[fi] = b0 | (b1 << 8) | (b2 << 16) | (b3 << 24);
}

// ---------- token preprocess: rmsnorm + act_quant(i8) + gate softmax ----------
__global__ __launch_bounds__(256) void preprocess_kernel(
    const float* __restrict__ x, const float* __restrict__ gw,
    const float* __restrict__ gb, const float* __restrict__ scales,
    int* __restrict__ qx, float* __restrict__ inv_sx, float* __restrict__ gates) {
  __shared__ float buf[4];
  const int t = blockIdx.x, tid = threadIdx.x;
  const float4 xv = ((const float4*)(x + (size_t)t * DIMS))[tid];
  float ss = xv.x * xv.x + xv.y * xv.y + xv.z * xv.z + xv.w * xv.w;
  ss = block_sum(ss, buf, tid);
  const float rr = 32.0f / fmaxf(sqrtf(ss), 1e-12f); // sqrt(1024)=32
  const float y0 = xv.x * rr, y1 = xv.y * rr, y2 = xv.z * rr, y3 = xv.w * rr;
  float am = fmaxf(fmaxf(fabsf(y0), fabsf(y1)), fmaxf(fabsf(y2), fabsf(y3)));
  am = block_max(am, buf, tid);
  const float aclip = fmaxf(am, 1e-5f);
  const float qsc = 127.0f / aclip;
  const float q0 = fminf(fmaxf(rintf(y0 * qsc), -128.0f), 127.0f);
  const float q1 = fminf(fmaxf(rintf(y1 * qsc), -128.0f), 127.0f);
  const float q2 = fminf(fmaxf(rintf(y2 * qsc), -128.0f), 127.0f);
  const float q3 = fminf(fmaxf(rintf(y3 * qsc), -128.0f), 127.0f);
  qx[t * 256 + tid] = (((int)q0) & 0xff) | ((((int)q1) & 0xff) << 8) |
                      ((((int)q2) & 0xff) << 16) | ((((int)q3) & 0xff) << 24);

  const float gqs = scales[33];
  float lg[NE];
  #pragma unroll
  for (int e = 0; e < NE; ++e) {
    const float4 gv = ((const float4*)(gw + e * DIMS))[tid];
    float t0 = fminf(fmaxf(rintf(gv.x * gqs), -1.0f), 1.0f);
    float t1 = fminf(fmaxf(rintf(gv.y * gqs), -1.0f), 1.0f);
    float t2 = fminf(fmaxf(rintf(gv.z * gqs), -1.0f), 1.0f);
    float t3 = fminf(fmaxf(rintf(gv.w * gqs), -1.0f), 1.0f);
    lg[e] = q0 * t0 + q1 * t1 + q2 * t2 + q3 * t3;
  }
  #pragma unroll
  for (int e = 0; e < NE; ++e) lg[e] = block_sum(lg[e], buf, tid);
  if (tid == 0) {
    const float gsabs = scales[32];
    const float isx = aclip / 127.0f;
    inv_sx[t] = isx;
    float l[NE], mx = -1e30f;
    #pragma unroll
    for (int e = 0; e < NE; ++e) { l[e] = lg[e] * (isx * gsabs) + gb[e]; mx = fmaxf(mx, l[e]); }
    float s = 0.0f;
    #pragma unroll
    for (int e = 0; e < NE; ++e) { l[e] = expf(l[e] - mx); s += l[e]; }
    const float inv = 1.0f / s;
    #pragma unroll
    for (int e = 0; e < NE; ++e) gates[t * NE + e] = l[e] * inv;
  }
}

// ---------- shared i8 GEMM core: 256x256 tile, BK=64, quad-buffer pipeline ----
// 512 threads = 8 waves (2M x 4N), per-wave 128x64 output, acc[8][4] i32x4.
// LDS: sA[4][256*64], sB[4][256*64] = 128 KiB. Iter t: stage tile t+3 into
// buf (t+3)&3 (== buf read at iter t-1, safe past that iter's barrier),
// compute tile t from buf t&3, then s_waitcnt vmcnt(8) (tiles t+2,t+3 remain
// in flight ACROSS the barrier). Tail peels vmcnt(4)/vmcnt(0).
// Swizzle: LDS[row][ck] holds global chunk ck ^ ((row>>1)&3).
template <int SA, int SB, int NT>
__device__ __forceinline__ void gemm_core_i8(
    const char* __restrict__ A, const char* __restrict__ Bm,
    int m0, int n0, char* sA, char* sB, i32x4 (&acc)[8][4]) {
  const int tid = threadIdx.x;               // 0..511
  const int lane = tid & 63;
  const int lm = lane & 15, lq = lane >> 4;
  const int wv = tid >> 6;                   // 0..7
  const int wr = (wv >> 2) * 128, wc = (wv & 3) * 64;

  // staging: tile = 256 rows x 64 B = 1024 chunks of 16 B; thread handles
  // chunks c0 = tid and c1 = 512+tid.  row = c>>2, LDS chunk = c&3,
  // global chunk = (c&3) ^ ((row>>1)&3)  (pre-swizzled source, linear dest).
  const int c0 = tid, c1 = 512 + tid;
  const int r0 = c0 >> 2, r1 = c1 >> 2;
  const int g0 = ((c0 & 3) ^ ((r0 >> 1) & 3)) << 4;
  const int g1 = ((c1 & 3) ^ ((r1 >> 1) & 3)) << 4;
  const char* gA0 = A + (size_t)(m0 + r0) * SA + g0;
  const char* gA1 = A + (size_t)(m0 + r1) * SA + g1;
  const char* gB0 = Bm + (size_t)(n0 + r0) * SB + g0;
  const char* gB1 = Bm + (size_t)(n0 + r1) * SB + g1;
  const int l0 = c0 * 16, l1 = c1 * 16;

  // fragment read offsets: row = (wr|wc) + i*16 + lm; (row>>1)&3 == (lm>>1)&3
  const int swz = (lq ^ ((lm >> 1) & 3)) << 4;
  const int aoff = (wr + lm) * 64 + swz;
  const int boff = (wc + lm) * 64 + swz;

#define STAGE_I8(j)                                           \
  do {                                                        \
    const int _b = (j) & 3; const int _k = (j) * 64;          \
    gl_lds16(gA0 + _k, sA + _b * 16384 + l0);                 \
    gl_lds16(gA1 + _k, sA + _b * 16384 + l1);                 \
    gl_lds16(gB0 + _k, sB + _b * 16384 + l0);                 \
    gl_lds16(gB1 + _k, sB + _b * 16384 + l1);                 \
  } while (0)

  STAGE_I8(0); STAGE_I8(1); STAGE_I8(2);          // 12 loads in flight
  asm volatile("s_waitcnt vmcnt(8)" ::: "memory"); // tile 0 landed
  __builtin_amdgcn_s_barrier();
  asm volatile("" ::: "memory");

  for (int t = 0; t < NT; ++t) {
    const int cur = t & 3;
    if (t + 3 < NT) STAGE_I8(t + 3);
    const char* bA = sA + cur * 16384;
    const char* bB = sB + cur * 16384;
    i32x4 av[8], bv[4];
    #pragma unroll
    for (int i = 0; i < 8; ++i) av[i] = *(const i32x4*)(bA + aoff + i * 1024);
    #pragma unroll
    for (int j = 0; j < 4; ++j) bv[j] = *(const i32x4*)(bB + boff + j * 1024);
    __builtin_amdgcn_s_setprio(1);
    #pragma unroll
    for (int i = 0; i < 8; ++i)
      #pragma unroll
      for (int j = 0; j < 4; ++j)
        acc[i][j] = __builtin_amdgcn_mfma_i32_16x16x64_i8(av[i], bv[j], acc[i][j], 0, 0, 0);
    __builtin_amdgcn_s_setprio(0);
    if (t < NT - 1) {
      // wait for tile t+1 only; keep later prefetches in flight
      if (t + 3 < NT)       { asm volatile("s_waitcnt vmcnt(8)" ::: "memory"); }
      else if (t + 3 == NT) { asm volatile("s_waitcnt vmcnt(4)" ::: "memory"); }
      else                  { asm volatile("s_waitcnt vmcnt(0)" ::: "memory"); }
      __builtin_amdgcn_s_barrier();
      asm volatile("" ::: "memory");
    }
  }
#undef STAGE_I8
}

// ---------- GEMM1: h = qx . w1q * s + b1 -> f16 ----------
__global__ __launch_bounds__(512, 2) void gemm1_kernel(
    const char* __restrict__ qx, const char* __restrict__ w1q,
    const float* __restrict__ scales, const float* __restrict__ inv_sx,
    const float* __restrict__ b1, char* __restrict__ aqa) {
  __shared__ __align__(16) char sA[4 * 16384];
  __shared__ __align__(16) char sB[4 * 16384];
  const int wg = blockIdx.x;
  const int e = wg & 7;            // expert -> XCD (L2 keeps qx resident)
  const int i2 = wg >> 3;          // 0..255
  const int yi = i2 & 15, xi = i2 >> 4;  // y fastest: B-panel reused in L2
  const int m0 = yi * 256, n0 = xi * 256;
  const char* Bm = w1q + (size_t)e * HID * DIMS;
  i32x4 acc[8][4] = {};
  gemm_core_i8<DIMS, DIMS, DIMS / 64>(qx, Bm, m0, n0, sA, sB, acc);

  const int tid = threadIdx.x, lane = tid & 63, wv = tid >> 6;
  const int wr = (wv >> 2) * 128, wc = (wv & 3) * 64, lm = lane & 15, lq = lane >> 4;
  char* obase = aqa + (size_t)e * T_TOK * ROWB;
  const float s1 = scales[e];
  float bb[4];
  #pragma unroll
  for (int j = 0; j < 4; ++j) bb[j] = b1[e * HID + n0 + wc + j * 16 + lm];
  #pragma unroll
  for (int i = 0; i < 8; ++i) {
    #pragma unroll
    for (int r = 0; r < 4; ++r) {
      const int row = m0 + wr + i * 16 + lq * 4 + r;
      const float rs = inv_sx[row] * s1;
      _Float16* orow = (_Float16*)(obase + (size_t)row * ROWB);
      #pragma unroll
      for (int j = 0; j < 4; ++j) {
        const int col = n0 + wc + j * 16 + lm;
        orow[col] = (_Float16)fmaf((float)acc[i][j][r], rs, bb[j]);
      }
    }
  }
}

// ---------- per-row GELU + rmsnorm + act_quant: f16 h-row -> i8 in place ----------
__global__ __launch_bounds__(256) void rowquant_kernel(
    char* __restrict__ aqa, float* __restrict__ inv_sa) {
  __shared__ float buf[4];
  const size_t R = blockIdx.x;
  char* rowb = aqa + R * ROWB;
  const int tid = threadIdx.x;
  f16x8 v0 = ((const f16x8*)rowb)[tid * 2];
  f16x8 v1 = ((const f16x8*)rowb)[tid * 2 + 1];
  float f[16];
  #pragma unroll
  for (int k = 0; k < 8; ++k) { f[k] = (float)v0[k]; f[8 + k] = (float)v1[k]; }
  #pragma unroll
  for (int k = 0; k < 16; ++k) f[k] = gelu_fast(f[k]);
  float ss = 0.0f;
  #pragma unroll
  for (int k = 0; k < 16; ++k) ss += f[k] * f[k];
  ss = block_sum(ss, buf, tid);           // barrier: reads complete before writes below
  const float rr = 64.0f / fmaxf(sqrtf(ss), 1e-12f); // sqrt(4096)=64
  float am = 0.0f;
  #pragma unroll
  for (int k = 0; k < 16; ++k) am = fmaxf(am, fabsf(f[k] * rr));
  am = block_max(am, buf, tid);
  const float aclip = fmaxf(am, 1e-5f);
  const float qsc = rr * 127.0f / aclip;
  int4 o;
  o.x = q8(f[0] * qsc) | (q8(f[1] * qsc) << 8) | (q8(f[2] * qsc) << 16) | (q8(f[3] * qsc) << 24);
  o.y = q8(f[4] * qsc) | (q8(f[5] * qsc) << 8) | (q8(f[6] * qsc) << 16) | (q8(f[7] * qsc) << 24);
  o.z = q8(f[8] * qsc) | (q8(f[9] * qsc) << 8) | (q8(f[10] * qsc) << 16) | (q8(f[11] * qsc) << 24);
  o.w = q8(f[12] * qsc) | (q8(f[13] * qsc) << 8) | (q8(f[14] * qsc) << 16) | (q8(f[15] * qsc) << 24);
  ((int4*)rowb)[tid] = o;
  if (tid == 0) inv_sa[R] = aclip / 127.0f;
}

// ---------- GEMM2: eout(f16) = gate*(qa.w2q*scale + b2) ----------
__global__ __launch_bounds__(512, 2) void gemm2_kernel(
    const char* __restrict__ aqa, const char* __restrict__ w2q,
    const float* __restrict__ scales, const float* __restrict__ inv_sa,
    const float* __restrict__ b2, const float* __restrict__ gates,
    void* __restrict__ dstv, int use_atomic) {
  __shared__ __align__(16) char sA[4 * 16384];
  __shared__ __align__(16) char sB[4 * 16384];
  const int wg = blockIdx.x;
  const int e = wg & 7;            // expert -> XCD (w2q expert = 4 MiB fits L2)
  const int i2 = wg >> 3;          // 0..63
  const int xi = i2 & 3, yi = i2 >> 2;  // x fastest: full B-expert resident
  const int m0 = yi * 256, n0 = xi * 256;
  const char* A = aqa + (size_t)e * T_TOK * ROWB;   // i8 in first 4096 B of each row
  const char* Bm = w2q + (size_t)e * DIMS * HID;
  i32x4 acc[8][4] = {};
  gemm_core_i8<(int)ROWB, HID, HID / 64>(A, Bm, m0, n0, sA, sB, acc);

  const int tid = threadIdx.x, lane = tid & 63, wv = tid >> 6;
  const int wr = (wv >> 2) * 128, wc = (wv & 3) * 64, lm = lane & 15, lq = lane >> 4;
  const float s2 = scales[16 + e];
  float bb[4];
  #pragma unroll
  for (int j = 0; j < 4; ++j) bb[j] = b2[e * DIMS + n0 + wc + j * 16 + lm];
  #pragma unroll
  for (int i = 0; i < 8; ++i) {
    #pragma unroll
    for (int r = 0; r < 4; ++r) {
      const int row = m0 + wr + i * 16 + lq * 4 + r;
      const float rs = inv_sa[(size_t)e * T_TOK + row] * s2;
      const float g = gates[row * NE + e];
      #pragma unroll
      for (int j = 0; j < 4; ++j) {
        const int col = n0 + wc + j * 16 + lm;
        const float v = g * fmaf((float)acc[i][j][r], rs, bb[j]);
        if (use_atomic) atomicAdd(&((float*)dstv)[(size_t)row * DIMS + col], v);
        else ((_Float16*)dstv)[((size_t)e * T_TOK + row) * DIMS + col] = (_Float16)v;
      }
    }
  }
}

// ---------- expert-sum reduce: f16 eout -> f32 out ----------
__global__ __launch_bounds__(256) void reduce_kernel(
    const f16x8* __restrict__ eout, float4* __restrict__ out) {
  const int i = blockIdx.x * 256 + threadIdx.x;  // over T*D/8 = 524288
  float s[8] = {};
  #pragma unroll
  for (int e = 0; e < NE; ++e) {
    f16x8 v = eout[(size_t)e * (T_TOK * DIMS / 8) + i];
    #pragma unroll
    for (int k = 0; k < 8; ++k) s[k] += (float)v[k];
  }
  float4 o0; o0.x = s[0]; o0.y = s[1]; o0.z = s[2]; o0.w = s[3];
  float4 o1; o1.x = s[4]; o1.y = s[5]; o1.z = s[6]; o1.w = s[7];
  out[i * 2]     = o0;
  out[i * 2 + 1] = o1;
}

// ---------- host orchestration ----------
extern "C" void kernel_launch(void* const* d_in, const int* in_sizes, int n_in,
                              void* d_out, int out_size, void* d_ws, size_t ws_size,
                              hipStream_t stream) {
  const float* x  = (const float*)d_in[0];
  const float* gw = (const float*)d_in[1];
  const float* gb = (const float*)d_in[2];
  const float* w1 = (const float*)d_in[3];
  const float* b1 = (const float*)d_in[4];
  const float* w2 = (const float*)d_in[5];
  const float* b2 = (const float*)d_in[6];
  float* outp = (float*)d_out;
  char* ws = (char*)d_ws;

  float* wsum   = (float*)(ws + 0);        // 17 floats
  float* scales = (float*)(ws + 256);      // 34 floats
  float* inv_sx = (float*)(ws + 4096);     // 4096 floats
  float* gates  = (float*)(ws + 20480);    // 32768 floats
  float* inv_sa = (float*)(ws + 151552);   // 32768 floats
  char*  qx     = ws + 282624;             // 4 MiB i8 [T][1024]
  char*  w1q    = ws + 4476928;            // 32 MiB i8
  char*  w2q    = ws + 38031360;           // 32 MiB i8
  char*  aqa    = ws + 71585792;           // 256 MiB: [E*T] rows of 8192 B
  char*  eout   = ws + 340021248;          // 64 MiB f16 [E][T][D] (optional)

  const bool has_eout = ws_size >= 340021248ull + 67108864ull;

  hipMemsetAsync(wsum, 0, 17 * sizeof(float), stream);
  wabs_sum_kernel<<<2048, 256, 0, stream>>>((const float4*)w1, 8388608, 20, wsum + 0);
  wabs_sum_kernel<<<2048, 256, 0, stream>>>((const float4*)w2, 8388608, 20, wsum + 8);
  wabs_sum_kernel<<<1,    256, 0, stream>>>((const float4*)gw, 2048,    30, wsum + 16);
  mkscales_kernel<<<1, 64, 0, stream>>>(wsum, scales);
  wquant_kernel<<<32768, 256, 0, stream>>>((const float4*)w1, (int*)w1q, 8388608, 20, scales + 8);
  wquant_kernel<<<32768, 256, 0, stream>>>((const float4*)w2, (int*)w2q, 8388608, 20, scales + 24);
  preprocess_kernel<<<4096, 256, 0, stream>>>(x, gw, gb, scales, (int*)qx, inv_sx, gates);

  gemm1_kernel<<<2048, 512, 0, stream>>>(qx, w1q, scales, inv_sx, b1, aqa);
  rowquant_kernel<<<32768, 256, 0, stream>>>(aqa, inv_sa);

  if (has_eout) {
    gemm2_kernel<<<512, 512, 0, stream>>>(
        aqa, w2q, scales, inv_sa, b2, gates, eout, 0);
    reduce_kernel<<<2048, 256, 0, stream>>>((const f16x8*)eout, (float4*)outp);
  } else {
    hipMemsetAsync(outp, 0, (size_t)out_size * sizeof(float), stream);
    gemm2_kernel<<<512, 512, 0, stream>>>(
        aqa, w2q, scales, inv_sa, b2, gates, outp, 1);
  }
}

// Round 2
// 927.525 us; speedup vs baseline: 1.0115x; 1.0115x over previous
//
#include <hip/hip_runtime.h>

// BitMoE: dense 8-expert BitNet MoE, T=4096 tokens, D=1024, H=4096.
// Round 6: i8 GEMM core restructured into the verified 8-phase-style schedule:
// each K-tile = 2 thin phases of {ds_read subtile; stage half-tile; barrier;
// lgkmcnt(0); setprio; 16 MFMA; setprio; barrier}. Per-wave lgkmcnt waits
// resolve in LDS-service order -> waves stagger, MFMA overlaps LDS service
// (m198->m201 mechanism). Counted vmcnt(8) once per K-tile (never 0 in steady
// state) on the proven race-free 4-ring of tile buffers. Numerics unchanged.

#define T_TOK 4096
#define DIMS  1024
#define HID   4096
#define NE    8
#define ROWB  8192ull   // byte stride of an h/qa row (4096 f16; i8 uses first 4096 B)

typedef __attribute__((ext_vector_type(4))) int       i32x4;
typedef __attribute__((ext_vector_type(8))) _Float16  f16x8;

// ---------- helpers ----------
__device__ __forceinline__ float block_sum(float v, float* buf, int tid) {
  #pragma unroll
  for (int o = 32; o > 0; o >>= 1) v += __shfl_down(v, o, 64);
  __syncthreads();
  if ((tid & 63) == 0) buf[tid >> 6] = v;
  __syncthreads();
  return buf[0] + buf[1] + buf[2] + buf[3];
}
__device__ __forceinline__ float block_max(float v, float* buf, int tid) {
  #pragma unroll
  for (int o = 32; o > 0; o >>= 1) { float t = __shfl_down(v, o, 64); v = fmaxf(v, t); }
  __syncthreads();
  if ((tid & 63) == 0) buf[tid >> 6] = v;
  __syncthreads();
  return fmaxf(fmaxf(buf[0], buf[1]), fmaxf(buf[2], buf[3]));
}

// async global->LDS, 16B per lane; LDS dest = wave-uniform base + lane*16
__device__ __forceinline__ void gl_lds16(const void* g, void* l) {
  __builtin_amdgcn_global_load_lds(
      (const __attribute__((address_space(1))) unsigned int*)g,
      (__attribute__((address_space(3))) unsigned int*)l, 16, 0, 0);
}

__device__ __forceinline__ int q8(float v) {
  return ((int)fminf(fmaxf(rintf(v), -128.0f), 127.0f)) & 0xff;
}

// branch-free erf, Abramowitz-Stegun 7.1.26
__device__ __forceinline__ float erf_fast(float x) {
  const float ax = fabsf(x);
  const float t = __builtin_amdgcn_rcpf(fmaf(0.3275911f, ax, 1.0f));
  float p = fmaf(1.061405429f, t, -1.453152027f);
  p = fmaf(p, t, 1.421413741f);
  p = fmaf(p, t, -0.284496736f);
  p = fmaf(p, t, 0.254829592f);
  p = p * t;
  const float e = __expf(-ax * ax);
  const float r = fmaf(-p, e, 1.0f);
  return copysignf(r, x);
}
__device__ __forceinline__ float gelu_fast(float h) {
  return 0.5f * h * (1.0f + erf_fast(h * 0.70710678118654752f));
}

// ---------- weight scale reduction: sum |w| per group ----------
__global__ __launch_bounds__(256) void wabs_sum_kernel(
    const float4* __restrict__ w, int n_f4, int shift, float* __restrict__ sums) {
  __shared__ float buf[4];
  const int tid = threadIdx.x;
  const int base = blockIdx.x * 4096;
  float acc = 0.0f;
  for (int k = 0; k < 16; ++k) {
    int fi = base + k * 256 + tid;
    if (fi < n_f4) {
      float4 v = w[fi];
      acc += fabsf(v.x) + fabsf(v.y) + fabsf(v.z) + fabsf(v.w);
    }
  }
  acc = block_sum(acc, buf, tid);
  if (tid == 0) atomicAdd(&sums[base >> shift], acc);
}

// ---------- scales ----------
__global__ void mkscales_kernel(const float* __restrict__ wsum, float* __restrict__ sc) {
  if (threadIdx.x == 0) {
    #pragma unroll
    for (int e = 0; e < NE; ++e) {
      float m1 = fmaxf(wsum[e] * (1.0f / 4194304.0f), 1e-5f);
      sc[e] = m1; sc[8 + e] = 1.0f / m1;
      float m2 = fmaxf(wsum[8 + e] * (1.0f / 4194304.0f), 1e-5f);
      sc[16 + e] = m2; sc[24 + e] = 1.0f / m2;
    }
    float mg = fmaxf(wsum[16] * (1.0f / 8192.0f), 1e-5f);
    sc[32] = mg; sc[33] = 1.0f / mg;
  }
}

// ---------- ternary weight quant -> i8 {-1,0,1} ----------
__global__ __launch_bounds__(256) void wquant_kernel(
    const float4* __restrict__ w, int* __restrict__ o, int n_f4, int shift,
    const float* __restrict__ qs) {
  int fi = blockIdx.x * 256 + threadIdx.x;
  if (fi >= n_f4) return;
  const float s = qs[fi >> shift];
  float4 v = w[fi];
  int b0 = ((int)fminf(fmaxf(rintf(v.x * s), -1.0f), 1.0f)) & 0xff;
  int b1 = ((int)fminf(fmaxf(rintf(v.y * s), -1.0f), 1.0f)) & 0xff;
  int b2 = ((int)fminf(fmaxf(rintf(v.z * s), -1.0f), 1.0f)) & 0xff;
  int b3 = ((int)fminf(fmaxf(rintf(v.w * s), -1.0f), 1.0f)) & 0xff;
  o[fi] = b0 | (b1 << 8) | (b2 << 16) | (b3 << 24);
}

// ---------- token preprocess: rmsnorm + act_quant(i8) + gate softmax ----------
__global__ __launch_bounds__(256) void preprocess_kernel(
    const float* __restrict__ x, const float* __restrict__ gw,
    const float* __restrict__ gb, const float* __restrict__ scales,
    int* __restrict__ qx, float* __restrict__ inv_sx, float* __restrict__ gates) {
  __shared__ float buf[4];
  const int t = blockIdx.x, tid = threadIdx.x;
  const float4 xv = ((const float4*)(x + (size_t)t * DIMS))[tid];
  float ss = xv.x * xv.x + xv.y * xv.y + xv.z * xv.z + xv.w * xv.w;
  ss = block_sum(ss, buf, tid);
  const float rr = 32.0f / fmaxf(sqrtf(ss), 1e-12f); // sqrt(1024)=32
  const float y0 = xv.x * rr, y1 = xv.y * rr, y2 = xv.z * rr, y3 = xv.w * rr;
  float am = fmaxf(fmaxf(fabsf(y0), fabsf(y1)), fmaxf(fabsf(y2), fabsf(y3)));
  am = block_max(am, buf, tid);
  const float aclip = fmaxf(am, 1e-5f);
  const float qsc = 127.0f / aclip;
  const float q0 = fminf(fmaxf(rintf(y0 * qsc), -128.0f), 127.0f);
  const float q1 = fminf(fmaxf(rintf(y1 * qsc), -128.0f), 127.0f);
  const float q2 = fminf(fmaxf(rintf(y2 * qsc), -128.0f), 127.0f);
  const float q3 = fminf(fmaxf(rintf(y3 * qsc), -128.0f), 127.0f);
  qx[t * 256 + tid] = (((int)q0) & 0xff) | ((((int)q1) & 0xff) << 8) |
                      ((((int)q2) & 0xff) << 16) | ((((int)q3) & 0xff) << 24);

  const float gqs = scales[33];
  float lg[NE];
  #pragma unroll
  for (int e = 0; e < NE; ++e) {
    const float4 gv = ((const float4*)(gw + e * DIMS))[tid];
    float t0 = fminf(fmaxf(rintf(gv.x * gqs), -1.0f), 1.0f);
    float t1 = fminf(fmaxf(rintf(gv.y * gqs), -1.0f), 1.0f);
    float t2 = fminf(fmaxf(rintf(gv.z * gqs), -1.0f), 1.0f);
    float t3 = fminf(fmaxf(rintf(gv.w * gqs), -1.0f), 1.0f);
    lg[e] = q0 * t0 + q1 * t1 + q2 * t2 + q3 * t3;
  }
  #pragma unroll
  for (int e = 0; e < NE; ++e) lg[e] = block_sum(lg[e], buf, tid);
  if (tid == 0) {
    const float gsabs = scales[32];
    const float isx = aclip / 127.0f;
    inv_sx[t] = isx;
    float l[NE], mx = -1e30f;
    #pragma unroll
    for (int e = 0; e < NE; ++e) { l[e] = lg[e] * (isx * gsabs) + gb[e]; mx = fmaxf(mx, l[e]); }
    float s = 0.0f;
    #pragma unroll
    for (int e = 0; e < NE; ++e) { l[e] = expf(l[e] - mx); s += l[e]; }
    const float inv = 1.0f / s;
    #pragma unroll
    for (int e = 0; e < NE; ++e) gates[t * NE + e] = l[e] * inv;
  }
}

// ---------- shared i8 GEMM core: 256x256 tile, BK=64, phase-interleaved ----
// 512 threads = 8 waves (2M x 4N), per-wave 128x64 output, acc[8][4] i32x4.
// LDS 4-ring: sA[4][256*64], sB[4][256*64] = 128 KiB; K-tile t lives in buf t&3.
// Per K-tile, TWO phases (template-granularity: 16 MFMA, 2 stage-loads,
// 8/4 ds_reads, 2 barriers per phase):
//   ph0: read avl[0..3],bv[0..3]; stage LO-half of tile t+3; barrier;
//        lgkmcnt(0); setprio; 16 MFMA acc[0..3][*]; setprio; barrier
//   ph1: read avh[0..3]; stage HI-half; vmcnt(8) [tail 4/0]; barrier;
//        lgkmcnt(0); setprio; 16 MFMA acc[4..7][*]; setprio; barrier
// Races: stage of t+3 writes buf (t-1)&3, fully read before tile t's first
// barrier; vmcnt(8)+barrier at tile end => tile t+1 landed for ALL waves
// before its reads. Counted vmcnt: tiles t+2,t+3 stay in flight across
// barriers. Swizzle ck^=(row>>1)&3, conflict-free (PMC=0).
template <int SA, int SB, int NT>
__device__ __forceinline__ void gemm_core_i8(
    const char* __restrict__ A, const char* __restrict__ Bm,
    int m0, int n0, char* sA, char* sB, i32x4 (&acc)[8][4]) {
  const int tid = threadIdx.x;               // 0..511
  const int lane = tid & 63;
  const int lm = lane & 15, lq = lane >> 4;
  const int wv = tid >> 6;                   // 0..7
  const int wr = (wv >> 2) * 128, wc = (wv & 3) * 64;

  // staging: tile = 256 rows x 64 B = 1024 chunks of 16 B; thread handles
  // chunk c0 = tid (rows 0..127, LO) and c1 = 512+tid (rows 128..255, HI).
  // row = c>>2, LDS chunk = c&3, global chunk = (c&3) ^ ((row>>1)&3).
  const int c0 = tid, c1 = 512 + tid;
  const int r0 = c0 >> 2, r1 = c1 >> 2;
  const int g0 = ((c0 & 3) ^ ((r0 >> 1) & 3)) << 4;
  const int g1 = ((c1 & 3) ^ ((r1 >> 1) & 3)) << 4;
  const char* gA0 = A + (size_t)(m0 + r0) * SA + g0;
  const char* gA1 = A + (size_t)(m0 + r1) * SA + g1;
  const char* gB0 = Bm + (size_t)(n0 + r0) * SB + g0;
  const char* gB1 = Bm + (size_t)(n0 + r1) * SB + g1;
  const int l0 = c0 * 16, l1 = c1 * 16;

  // fragment read offsets: row = (wr|wc) + i*16 + lm; (row>>1)&3 == (lm>>1)&3
  const int swz = (lq ^ ((lm >> 1) & 3)) << 4;
  const int aoff = (wr + lm) * 64 + swz;
  const int boff = (wc + lm) * 64 + swz;

#define STAGE_LO(j)                                           \
  do {                                                        \
    const int _b = (j) & 3; const int _k = (j) * 64;          \
    gl_lds16(gA0 + _k, sA + _b * 16384 + l0);                 \
    gl_lds16(gB0 + _k, sB + _b * 16384 + l0);                 \
  } while (0)
#define STAGE_HI(j)                                           \
  do {                                                        \
    const int _b = (j) & 3; const int _k = (j) * 64;          \
    gl_lds16(gA1 + _k, sA + _b * 16384 + l1);                 \
    gl_lds16(gB1 + _k, sB + _b * 16384 + l1);                 \
  } while (0)

  // prologue: tiles 0,1,2 in flight (12 loads); tile 0 landed after vmcnt(8)
  STAGE_LO(0); STAGE_HI(0);
  STAGE_LO(1); STAGE_HI(1);
  STAGE_LO(2); STAGE_HI(2);
  asm volatile("s_waitcnt vmcnt(8)" ::: "memory");
  __builtin_amdgcn_s_barrier();
  asm volatile("" ::: "memory");

  for (int t = 0; t < NT; ++t) {
    const char* bA = sA + (t & 3) * 16384;
    const char* bB = sB + (t & 3) * 16384;
    i32x4 avl[4], avh[4], bv[4];
    // ---- phase 0 ----
    #pragma unroll
    for (int i = 0; i < 4; ++i) avl[i] = *(const i32x4*)(bA + aoff + i * 1024);
    #pragma unroll
    for (int j = 0; j < 4; ++j) bv[j] = *(const i32x4*)(bB + boff + j * 1024);
    if (t + 3 < NT) STAGE_LO(t + 3);
    __builtin_amdgcn_s_barrier();
    asm volatile("s_waitcnt lgkmcnt(0)" ::: "memory");
    __builtin_amdgcn_s_setprio(1);
    #pragma unroll
    for (int i = 0; i < 4; ++i)
      #pragma unroll
      for (int j = 0; j < 4; ++j)
        acc[i][j] = __builtin_amdgcn_mfma_i32_16x16x64_i8(avl[i], bv[j], acc[i][j], 0, 0, 0);
    __builtin_amdgcn_s_setprio(0);
    __builtin_amdgcn_s_barrier();
    asm volatile("" ::: "memory");
    // ---- phase 1 ----
    #pragma unroll
    for (int i = 0; i < 4; ++i) avh[i] = *(const i32x4*)(bA + aoff + (4 + i) * 1024);
    if (t + 3 < NT) STAGE_HI(t + 3);
    // end-of-tile wait: ensure tile t+1 landed for this wave; barrier makes
    // it all-waves. Keep tiles t+2,t+3 in flight.
    if (t + 3 < NT)      { asm volatile("s_waitcnt vmcnt(8)" ::: "memory"); }
    else if (t + 2 < NT) { asm volatile("s_waitcnt vmcnt(4)" ::: "memory"); }
    else                 { asm volatile("s_waitcnt vmcnt(0)" ::: "memory"); }
    __builtin_amdgcn_s_barrier();
    asm volatile("s_waitcnt lgkmcnt(0)" ::: "memory");
    __builtin_amdgcn_s_setprio(1);
    #pragma unroll
    for (int i = 0; i < 4; ++i)
      #pragma unroll
      for (int j = 0; j < 4; ++j)
        acc[4 + i][j] = __builtin_amdgcn_mfma_i32_16x16x64_i8(avh[i], bv[j], acc[4 + i][j], 0, 0, 0);
    __builtin_amdgcn_s_setprio(0);
    __builtin_amdgcn_s_barrier();
    asm volatile("" ::: "memory");
  }
#undef STAGE_LO
#undef STAGE_HI
}

// ---------- GEMM1: h = qx . w1q * s + b1 -> f16 ----------
__global__ __launch_bounds__(512, 2) void gemm1_kernel(
    const char* __restrict__ qx, const char* __restrict__ w1q,
    const float* __restrict__ scales, const float* __restrict__ inv_sx,
    const float* __restrict__ b1, char* __restrict__ aqa) {
  __shared__ __align__(16) char sA[4 * 16384];
  __shared__ __align__(16) char sB[4 * 16384];
  const int wg = blockIdx.x;
  const int e = wg & 7;            // expert -> XCD (L2 keeps qx resident)
  const int i2 = wg >> 3;          // 0..255
  const int yi = i2 & 15, xi = i2 >> 4;  // y fastest: B-panel reused in L2
  const int m0 = yi * 256, n0 = xi * 256;
  const char* Bm = w1q + (size_t)e * HID * DIMS;
  i32x4 acc[8][4] = {};
  gemm_core_i8<DIMS, DIMS, DIMS / 64>(qx, Bm, m0, n0, sA, sB, acc);

  const int tid = threadIdx.x, lane = tid & 63, wv = tid >> 6;
  const int wr = (wv >> 2) * 128, wc = (wv & 3) * 64, lm = lane & 15, lq = lane >> 4;
  char* obase = aqa + (size_t)e * T_TOK * ROWB;
  const float s1 = scales[e];
  float bb[4];
  #pragma unroll
  for (int j = 0; j < 4; ++j) bb[j] = b1[e * HID + n0 + wc + j * 16 + lm];
  #pragma unroll
  for (int i = 0; i < 8; ++i) {
    #pragma unroll
    for (int r = 0; r < 4; ++r) {
      const int row = m0 + wr + i * 16 + lq * 4 + r;
      const float rs = inv_sx[row] * s1;
      _Float16* orow = (_Float16*)(obase + (size_t)row * ROWB);
      #pragma unroll
      for (int j = 0; j < 4; ++j) {
        const int col = n0 + wc + j * 16 + lm;
        orow[col] = (_Float16)fmaf((float)acc[i][j][r], rs, bb[j]);
      }
    }
  }
}

// ---------- per-row GELU + rmsnorm + act_quant: f16 h-row -> i8 in place ----------
__global__ __launch_bounds__(256) void rowquant_kernel(
    char* __restrict__ aqa, float* __restrict__ inv_sa) {
  __shared__ float buf[4];
  const size_t R = blockIdx.x;
  char* rowb = aqa + R * ROWB;
  const int tid = threadIdx.x;
  f16x8 v0 = ((const f16x8*)rowb)[tid * 2];
  f16x8 v1 = ((const f16x8*)rowb)[tid * 2 + 1];
  float f[16];
  #pragma unroll
  for (int k = 0; k < 8; ++k) { f[k] = (float)v0[k]; f[8 + k] = (float)v1[k]; }
  #pragma unroll
  for (int k = 0; k < 16; ++k) f[k] = gelu_fast(f[k]);
  float ss = 0.0f;
  #pragma unroll
  for (int k = 0; k < 16; ++k) ss += f[k] * f[k];
  ss = block_sum(ss, buf, tid);           // barrier: reads complete before writes below
  const float rr = 64.0f / fmaxf(sqrtf(ss), 1e-12f); // sqrt(4096)=64
  float am = 0.0f;
  #pragma unroll
  for (int k = 0; k < 16; ++k) am = fmaxf(am, fabsf(f[k] * rr));
  am = block_max(am, buf, tid);
  const float aclip = fmaxf(am, 1e-5f);
  const float qsc = rr * 127.0f / aclip;
  int4 o;
  o.x = q8(f[0] * qsc) | (q8(f[1] * qsc) << 8) | (q8(f[2] * qsc) << 16) | (q8(f[3] * qsc) << 24);
  o.y = q8(f[4] * qsc) | (q8(f[5] * qsc) << 8) | (q8(f[6] * qsc) << 16) | (q8(f[7] * qsc) << 24);
  o.z = q8(f[8] * qsc) | (q8(f[9] * qsc) << 8) | (q8(f[10] * qsc) << 16) | (q8(f[11] * qsc) << 24);
  o.w = q8(f[12] * qsc) | (q8(f[13] * qsc) << 8) | (q8(f[14] * qsc) << 16) | (q8(f[15] * qsc) << 24);
  ((int4*)rowb)[tid] = o;
  if (tid == 0) inv_sa[R] = aclip / 127.0f;
}

// ---------- GEMM2: eout(f16) = gate*(qa.w2q*scale + b2) ----------
__global__ __launch_bounds__(512, 2) void gemm2_kernel(
    const char* __restrict__ aqa, const char* __restrict__ w2q,
    const float* __restrict__ scales, const float* __restrict__ inv_sa,
    const float* __restrict__ b2, const float* __restrict__ gates,
    void* __restrict__ dstv, int use_atomic) {
  __shared__ __align__(16) char sA[4 * 16384];
  __shared__ __align__(16) char sB[4 * 16384];
  const int wg = blockIdx.x;
  const int e = wg & 7;            // expert -> XCD (w2q expert = 4 MiB fits L2)
  const int i2 = wg >> 3;          // 0..63
  const int xi = i2 & 3, yi = i2 >> 2;  // x fastest: full B-expert resident
  const int m0 = yi * 256, n0 = xi * 256;
  const char* A = aqa + (size_t)e * T_TOK * ROWB;   // i8 in first 4096 B of each row
  const char* Bm = w2q + (size_t)e * DIMS * HID;
  i32x4 acc[8][4] = {};
  gemm_core_i8<(int)ROWB, HID, HID / 64>(A, Bm, m0, n0, sA, sB, acc);

  const int tid = threadIdx.x, lane = tid & 63, wv = tid >> 6;
  const int wr = (wv >> 2) * 128, wc = (wv & 3) * 64, lm = lane & 15, lq = lane >> 4;
  const float s2 = scales[16 + e];
  float bb[4];
  #pragma unroll
  for (int j = 0; j < 4; ++j) bb[j] = b2[e * DIMS + n0 + wc + j * 16 + lm];
  #pragma unroll
  for (int i = 0; i < 8; ++i) {
    #pragma unroll
    for (int r = 0; r < 4; ++r) {
      const int row = m0 + wr + i * 16 + lq * 4 + r;
      const float rs = inv_sa[(size_t)e * T_TOK + row] * s2;
      const float g = gates[row * NE + e];
      #pragma unroll
      for (int j = 0; j < 4; ++j) {
        const int col = n0 + wc + j * 16 + lm;
        const float v = g * fmaf((float)acc[i][j][r], rs, bb[j]);
        if (use_atomic) atomicAdd(&((float*)dstv)[(size_t)row * DIMS + col], v);
        else ((_Float16*)dstv)[((size_t)e * T_TOK + row) * DIMS + col] = (_Float16)v;
      }
    }
  }
}

// ---------- expert-sum reduce: f16 eout -> f32 out ----------
__global__ __launch_bounds__(256) void reduce_kernel(
    const f16x8* __restrict__ eout, float4* __restrict__ out) {
  const int i = blockIdx.x * 256 + threadIdx.x;  // over T*D/8 = 524288
  float s[8] = {};
  #pragma unroll
  for (int e = 0; e < NE; ++e) {
    f16x8 v = eout[(size_t)e * (T_TOK * DIMS / 8) + i];
    #pragma unroll
    for (int k = 0; k < 8; ++k) s[k] += (float)v[k];
  }
  float4 o0; o0.x = s[0]; o0.y = s[1]; o0.z = s[2]; o0.w = s[3];
  float4 o1; o1.x = s[4]; o1.y = s[5]; o1.z = s[6]; o1.w = s[7];
  out[i * 2]     = o0;
  out[i * 2 + 1] = o1;
}

// ---------- host orchestration ----------
extern "C" void kernel_launch(void* const* d_in, const int* in_sizes, int n_in,
                              void* d_out, int out_size, void* d_ws, size_t ws_size,
                              hipStream_t stream) {
  const float* x  = (const float*)d_in[0];
  const float* gw = (const float*)d_in[1];
  const float* gb = (const float*)d_in[2];
  const float* w1 = (const float*)d_in[3];
  const float* b1 = (const float*)d_in[4];
  const float* w2 = (const float*)d_in[5];
  const float* b2 = (const float*)d_in[6];
  float* outp = (float*)d_out;
  char* ws = (char*)d_ws;

  float* wsum   = (float*)(ws + 0);        // 17 floats
  float* scales = (float*)(ws + 256);      // 34 floats
  float* inv_sx = (float*)(ws + 4096);     // 4096 floats
  float* gates  = (float*)(ws + 20480);    // 32768 floats
  float* inv_sa = (float*)(ws + 151552);   // 32768 floats
  char*  qx     = ws + 282624;             // 4 MiB i8 [T][1024]
  char*  w1q    = ws + 4476928;            // 32 MiB i8
  char*  w2q    = ws + 38031360;           // 32 MiB i8
  char*  aqa    = ws + 71585792;           // 256 MiB: [E*T] rows of 8192 B
  char*  eout   = ws + 340021248;          // 64 MiB f16 [E][T][D] (optional)

  const bool has_eout = ws_size >= 340021248ull + 67108864ull;

  hipMemsetAsync(wsum, 0, 17 * sizeof(float), stream);
  wabs_sum_kernel<<<2048, 256, 0, stream>>>((const float4*)w1, 8388608, 20, wsum + 0);
  wabs_sum_kernel<<<2048, 256, 0, stream>>>((const float4*)w2, 8388608, 20, wsum + 8);
  wabs_sum_kernel<<<1,    256, 0, stream>>>((const float4*)gw, 2048,    30, wsum + 16);
  mkscales_kernel<<<1, 64, 0, stream>>>(wsum, scales);
  wquant_kernel<<<32768, 256, 0, stream>>>((const float4*)w1, (int*)w1q, 8388608, 20, scales + 8);
  wquant_kernel<<<32768, 256, 0, stream>>>((const float4*)w2, (int*)w2q, 8388608, 20, scales + 24);
  preprocess_kernel<<<4096, 256, 0, stream>>>(x, gw, gb, scales, (int*)qx, inv_sx, gates);

  gemm1_kernel<<<2048, 512, 0, stream>>>(qx, w1q, scales, inv_sx, b1, aqa);
  rowquant_kernel<<<32768, 256, 0, stream>>>(aqa, inv_sa);

  if (has_eout) {
    gemm2_kernel<<<512, 512, 0, stream>>>(
        aqa, w2q, scales, inv_sa, b2, gates, eout, 0);
    reduce_kernel<<<2048, 256, 0, stream>>>((const f16x8*)eout, (float4*)outp);
  } else {
    hipMemsetAsync(outp, 0, (size_t)out_size * sizeof(float), stream);
    gemm2_kernel<<<512, 512, 0, stream>>>(
        aqa, w2q, scales, inv_sa, b2, gates, outp, 1);
  }
}

// Round 3
// 891.930 us; speedup vs baseline: 1.0519x; 1.0399x over previous
//
#include <hip/hip_runtime.h>

// BitMoE: dense 8-expert BitNet MoE, T=4096 tokens, D=1024, H=4096.
// Round 7: REVERT both GEMMs to the round-0 structure (256x128 tiles, BK=128,
// 256 threads, 2-3 blocks/CU -- measured 890 us; the 512-thread deep-pipeline
// variants phase-locked one barrier group per CU and regressed). Single new
// lever: 1-D grid with expert->XCD mapping (e = wg&7; round-1 counters proved
// this reaches ideal FETCH on gemm1: 148 MB). gemm2's w2q expert slice = 4 MiB
// = one XCD L2; x-fastest ordering keeps it resident (round-0 FETCH was 542 MB
// vs ~170 ideal). Nontemporal stores on streaming outputs (h, eout) protect L2.

#define T_TOK 4096
#define DIMS  1024
#define HID   4096
#define NE    8
#define ROWB  8192ull   // byte stride of an h/qa row (4096 f16; i8 uses first 4096 B)

typedef __attribute__((ext_vector_type(4))) int       i32x4;
typedef __attribute__((ext_vector_type(8))) _Float16  f16x8;

// ---------- helpers ----------
__device__ __forceinline__ float block_sum(float v, float* buf, int tid) {
  #pragma unroll
  for (int o = 32; o > 0; o >>= 1) v += __shfl_down(v, o, 64);
  __syncthreads();
  if ((tid & 63) == 0) buf[tid >> 6] = v;
  __syncthreads();
  return buf[0] + buf[1] + buf[2] + buf[3];
}
__device__ __forceinline__ float block_max(float v, float* buf, int tid) {
  #pragma unroll
  for (int o = 32; o > 0; o >>= 1) { float t = __shfl_down(v, o, 64); v = fmaxf(v, t); }
  __syncthreads();
  if ((tid & 63) == 0) buf[tid >> 6] = v;
  __syncthreads();
  return fmaxf(fmaxf(buf[0], buf[1]), fmaxf(buf[2], buf[3]));
}

// async global->LDS, 16B per lane; LDS dest = wave-uniform base + lane*16
__device__ __forceinline__ void gl_lds16(const void* g, void* l) {
  __builtin_amdgcn_global_load_lds(
      (const __attribute__((address_space(1))) unsigned int*)g,
      (__attribute__((address_space(3))) unsigned int*)l, 16, 0, 0);
}

__device__ __forceinline__ int q8(float v) {
  return ((int)fminf(fmaxf(rintf(v), -128.0f), 127.0f)) & 0xff;
}

// branch-free erf, Abramowitz-Stegun 7.1.26
__device__ __forceinline__ float erf_fast(float x) {
  const float ax = fabsf(x);
  const float t = __builtin_amdgcn_rcpf(fmaf(0.3275911f, ax, 1.0f));
  float p = fmaf(1.061405429f, t, -1.453152027f);
  p = fmaf(p, t, 1.421413741f);
  p = fmaf(p, t, -0.284496736f);
  p = fmaf(p, t, 0.254829592f);
  p = p * t;
  const float e = __expf(-ax * ax);
  const float r = fmaf(-p, e, 1.0f);
  return copysignf(r, x);
}
__device__ __forceinline__ float gelu_fast(float h) {
  return 0.5f * h * (1.0f + erf_fast(h * 0.70710678118654752f));
}

// swizzled fragment address: row stride 128 B, chunk' = chunk ^ (row&7)
__device__ __forceinline__ const i32x4* frag(const char* s, int row, int ckW) {
  return (const i32x4*)&s[row * 128 + ((ckW ^ (row & 7)) << 4)];
}

// ---------- weight scale reduction: sum |w| per group ----------
__global__ __launch_bounds__(256) void wabs_sum_kernel(
    const float4* __restrict__ w, int n_f4, int shift, float* __restrict__ sums) {
  __shared__ float buf[4];
  const int tid = threadIdx.x;
  const int base = blockIdx.x * 4096;
  float acc = 0.0f;
  for (int k = 0; k < 16; ++k) {
    int fi = base + k * 256 + tid;
    if (fi < n_f4) {
      float4 v = w[fi];
      acc += fabsf(v.x) + fabsf(v.y) + fabsf(v.z) + fabsf(v.w);
    }
  }
  acc = block_sum(acc, buf, tid);
  if (tid == 0) atomicAdd(&sums[base >> shift], acc);
}

// ---------- scales ----------
__global__ void mkscales_kernel(const float* __restrict__ wsum, float* __restrict__ sc) {
  if (threadIdx.x == 0) {
    #pragma unroll
    for (int e = 0; e < NE; ++e) {
      float m1 = fmaxf(wsum[e] * (1.0f / 4194304.0f), 1e-5f);
      sc[e] = m1; sc[8 + e] = 1.0f / m1;
      float m2 = fmaxf(wsum[8 + e] * (1.0f / 4194304.0f), 1e-5f);
      sc[16 + e] = m2; sc[24 + e] = 1.0f / m2;
    }
    float mg = fmaxf(wsum[16] * (1.0f / 8192.0f), 1e-5f);
    sc[32] = mg; sc[33] = 1.0f / mg;
  }
}

// ---------- ternary weight quant -> i8 {-1,0,1} ----------
__global__ __launch_bounds__(256) void wquant_kernel(
    const float4* __restrict__ w, int* __restrict__ o, int n_f4, int shift,
    const float* __restrict__ qs) {
  int fi = blockIdx.x * 256 + threadIdx.x;
  if (fi >= n_f4) return;
  const float s = qs[fi >> shift];
  float4 v = w[fi];
  int b0 = ((int)fminf(fmaxf(rintf(v.x * s), -1.0f), 1.0f)) & 0xff;
  int b1 = ((int)fminf(fmaxf(rintf(v.y * s), -1.0f), 1.0f)) & 0xff;
  int b2 = ((int)fminf(fmaxf(rintf(v.z * s), -1.0f), 1.0f)) & 0xff;
  int b3 = ((int)fminf(fmaxf(rintf(v.w * s), -1.0f), 1.0f)) & 0xff;
  o[fi] = b0 | (b1 << 8) | (b2 << 16) | (b3 << 24);
}

// ---------- token preprocess: rmsnorm + act_quant(i8) + gate softmax ----------
__global__ __launch_bounds__(256) void preprocess_kernel(
    const float* __restrict__ x, const float* __restrict__ gw,
    const float* __restrict__ gb, const float* __restrict__ scales,
    int* __restrict__ qx, float* __restrict__ inv_sx, float* __restrict__ gates) {
  __shared__ float buf[4];
  const int t = blockIdx.x, tid = threadIdx.x;
  const float4 xv = ((const float4*)(x + (size_t)t * DIMS))[tid];
  float ss = xv.x * xv.x + xv.y * xv.y + xv.z * xv.z + xv.w * xv.w;
  ss = block_sum(ss, buf, tid);
  const float rr = 32.0f / fmaxf(sqrtf(ss), 1e-12f); // sqrt(1024)=32
  const float y0 = xv.x * rr, y1 = xv.y * rr, y2 = xv.z * rr, y3 = xv.w * rr;
  float am = fmaxf(fmaxf(fabsf(y0), fabsf(y1)), fmaxf(fabsf(y2), fabsf(y3)));
  am = block_max(am, buf, tid);
  const float aclip = fmaxf(am, 1e-5f);
  const float qsc = 127.0f / aclip;
  const float q0 = fminf(fmaxf(rintf(y0 * qsc), -128.0f), 127.0f);
  const float q1 = fminf(fmaxf(rintf(y1 * qsc), -128.0f), 127.0f);
  const float q2 = fminf(fmaxf(rintf(y2 * qsc), -128.0f), 127.0f);
  const float q3 = fminf(fmaxf(rintf(y3 * qsc), -128.0f), 127.0f);
  qx[t * 256 + tid] = (((int)q0) & 0xff) | ((((int)q1) & 0xff) << 8) |
                      ((((int)q2) & 0xff) << 16) | ((((int)q3) & 0xff) << 24);

  const float gqs = scales[33];
  float lg[NE];
  #pragma unroll
  for (int e = 0; e < NE; ++e) {
    const float4 gv = ((const float4*)(gw + e * DIMS))[tid];
    float t0 = fminf(fmaxf(rintf(gv.x * gqs), -1.0f), 1.0f);
    float t1 = fminf(fmaxf(rintf(gv.y * gqs), -1.0f), 1.0f);
    float t2 = fminf(fmaxf(rintf(gv.z * gqs), -1.0f), 1.0f);
    float t3 = fminf(fmaxf(rintf(gv.w * gqs), -1.0f), 1.0f);
    lg[e] = q0 * t0 + q1 * t1 + q2 * t2 + q3 * t3;
  }
  #pragma unroll
  for (int e = 0; e < NE; ++e) lg[e] = block_sum(lg[e], buf, tid);
  if (tid == 0) {
    const float gsabs = scales[32];
    const float isx = aclip / 127.0f;
    inv_sx[t] = isx;
    float l[NE], mx = -1e30f;
    #pragma unroll
    for (int e = 0; e < NE; ++e) { l[e] = lg[e] * (isx * gsabs) + gb[e]; mx = fmaxf(mx, l[e]); }
    float s = 0.0f;
    #pragma unroll
    for (int e = 0; e < NE; ++e) { l[e] = expf(l[e] - mx); s += l[e]; }
    const float inv = 1.0f / s;
    #pragma unroll
    for (int e = 0; e < NE; ++e) gates[t * NE + e] = l[e] * inv;
  }
}

// ---------- GEMM1 (i8, 256x128, BK=128): h = qx . w1q * s + b1 -> f16 ----------
// 1-D grid 4096: e = wg&7 (expert->XCD), y fastest within expert (qx 4 MiB
// stays resident in the XCD L2; w1q streamed once).
__global__ __launch_bounds__(256, 2) void gemm1_kernel(
    const char* __restrict__ qx, const char* __restrict__ w1q,
    const float* __restrict__ scales, const float* __restrict__ inv_sx,
    const float* __restrict__ b1, char* __restrict__ aqa) {
  __shared__ __align__(16) char sA[256 * 128];
  __shared__ __align__(16) char sB[128 * 128];
  const int wg = blockIdx.x;
  const int e = wg & 7;
  const int i2 = wg >> 3;                  // 0..511
  const int yi = i2 & 15, xi = i2 >> 4;    // y fastest
  const int n0 = xi * 128, m0 = yi * 256;
  const char* A = qx;                                   // [T][1024] i8
  const char* Bm = w1q + (size_t)e * HID * DIMS;        // [H][1024] i8
  char* obase = aqa + (size_t)e * T_TOK * ROWB;
  const int tid = threadIdx.x, lane = tid & 63, wv = tid >> 6;
  const int wr = (wv >> 1) * 128, wc = (wv & 1) * 64, lm = lane & 15, lq = lane >> 4;
  i32x4 acc[8][4] = {};
  for (int k0 = 0; k0 < DIMS; k0 += 128) {
    #pragma unroll
    for (int it = 0; it < 8; ++it) {   // sA: 256 rows x 128 B
      const int c = it * 256 + tid;
      const int row = c >> 3, ckG = (c & 7) ^ (row & 7);
      gl_lds16(A + (size_t)(m0 + row) * DIMS + k0 + ckG * 16, &sA[c * 16]);
    }
    #pragma unroll
    for (int it = 0; it < 4; ++it) {   // sB: 128 rows x 128 B
      const int c = it * 256 + tid;
      const int row = c >> 3, ckG = (c & 7) ^ (row & 7);
      gl_lds16(Bm + (size_t)(n0 + row) * DIMS + k0 + ckG * 16, &sB[c * 16]);
    }
    __syncthreads();
    #pragma unroll
    for (int kk = 0; kk < 2; ++kk) {
      i32x4 av[8], bv[4];
      const int ckW = kk * 4 + lq;
      #pragma unroll
      for (int i = 0; i < 8; ++i) av[i] = *frag(sA, wr + i * 16 + lm, ckW);
      #pragma unroll
      for (int j = 0; j < 4; ++j) bv[j] = *frag(sB, wc + j * 16 + lm, ckW);
      #pragma unroll
      for (int i = 0; i < 8; ++i)
        #pragma unroll
        for (int j = 0; j < 4; ++j)
          acc[i][j] = __builtin_amdgcn_mfma_i32_16x16x64_i8(av[i], bv[j], acc[i][j], 0, 0, 0);
    }
    __syncthreads();
  }
  const float s1 = scales[e];
  float bb[4];
  #pragma unroll
  for (int j = 0; j < 4; ++j) bb[j] = b1[e * HID + n0 + wc + j * 16 + lm];
  #pragma unroll
  for (int i = 0; i < 8; ++i) {
    #pragma unroll
    for (int r = 0; r < 4; ++r) {
      const int row = m0 + wr + i * 16 + lq * 4 + r;
      const float rs = inv_sx[row] * s1;
      _Float16* orow = (_Float16*)(obase + (size_t)row * ROWB);
      #pragma unroll
      for (int j = 0; j < 4; ++j) {
        const int col = n0 + wc + j * 16 + lm;
        __builtin_nontemporal_store((_Float16)fmaf((float)acc[i][j][r], rs, bb[j]),
                                    &orow[col]);
      }
    }
  }
}

// ---------- per-row GELU + rmsnorm + act_quant: f16 h-row -> i8 in place ----------
__global__ __launch_bounds__(256) void rowquant_kernel(
    char* __restrict__ aqa, float* __restrict__ inv_sa) {
  __shared__ float buf[4];
  const size_t R = blockIdx.x;
  char* rowb = aqa + R * ROWB;
  const int tid = threadIdx.x;
  f16x8 v0 = ((const f16x8*)rowb)[tid * 2];
  f16x8 v1 = ((const f16x8*)rowb)[tid * 2 + 1];
  float f[16];
  #pragma unroll
  for (int k = 0; k < 8; ++k) { f[k] = (float)v0[k]; f[8 + k] = (float)v1[k]; }
  #pragma unroll
  for (int k = 0; k < 16; ++k) f[k] = gelu_fast(f[k]);   // GELU lives here (mem-bound kernel)
  float ss = 0.0f;
  #pragma unroll
  for (int k = 0; k < 16; ++k) ss += f[k] * f[k];
  ss = block_sum(ss, buf, tid);           // barrier: reads complete before writes below
  const float rr = 64.0f / fmaxf(sqrtf(ss), 1e-12f); // sqrt(4096)=64
  float am = 0.0f;
  #pragma unroll
  for (int k = 0; k < 16; ++k) am = fmaxf(am, fabsf(f[k] * rr));
  am = block_max(am, buf, tid);
  const float aclip = fmaxf(am, 1e-5f);
  const float qsc = rr * 127.0f / aclip;
  int4 o;
  o.x = q8(f[0] * qsc) | (q8(f[1] * qsc) << 8) | (q8(f[2] * qsc) << 16) | (q8(f[3] * qsc) << 24);
  o.y = q8(f[4] * qsc) | (q8(f[5] * qsc) << 8) | (q8(f[6] * qsc) << 16) | (q8(f[7] * qsc) << 24);
  o.z = q8(f[8] * qsc) | (q8(f[9] * qsc) << 8) | (q8(f[10] * qsc) << 16) | (q8(f[11] * qsc) << 24);
  o.w = q8(f[12] * qsc) | (q8(f[13] * qsc) << 8) | (q8(f[14] * qsc) << 16) | (q8(f[15] * qsc) << 24);
  ((int4*)rowb)[tid] = o;
  if (tid == 0) inv_sa[R] = aclip / 127.0f;
}

// ---------- GEMM2 (i8, 256x128, BK=128): eout(f16) = gate*(qa.w2q*scale + b2) ----
// 1-D grid 1024: e = wg&7 (expert->XCD; w2q[e] = 4 MiB = one L2), x fastest
// within expert (full weight expert resident, A-panel shared by consecutive wgs).
__global__ __launch_bounds__(256, 2) void gemm2_kernel(
    const char* __restrict__ aqa, const char* __restrict__ w2q,
    const float* __restrict__ scales, const float* __restrict__ inv_sa,
    const float* __restrict__ b2, const float* __restrict__ gates,
    void* __restrict__ dstv, int use_atomic) {
  __shared__ __align__(16) char sA[256 * 128];
  __shared__ __align__(16) char sB[128 * 128];
  const int wg = blockIdx.x;
  const int e = wg & 7;
  const int i2 = wg >> 3;                  // 0..127
  const int xi = i2 & 7, yi = i2 >> 3;     // x fastest
  const int n0 = xi * 128, m0 = yi * 256;
  const char* A = aqa + (size_t)e * T_TOK * ROWB;        // [T] rows, i8 in first 4096 B
  const char* Bm = w2q + (size_t)e * DIMS * HID;         // [D][4096] i8
  const int tid = threadIdx.x, lane = tid & 63, wv = tid >> 6;
  const int wr = (wv >> 1) * 128, wc = (wv & 1) * 64, lm = lane & 15, lq = lane >> 4;
  i32x4 acc[8][4] = {};
  for (int k0 = 0; k0 < HID; k0 += 128) {
    #pragma unroll
    for (int it = 0; it < 8; ++it) {
      const int c = it * 256 + tid;
      const int row = c >> 3, ckG = (c & 7) ^ (row & 7);
      gl_lds16(A + (size_t)(m0 + row) * ROWB + k0 + ckG * 16, &sA[c * 16]);
    }
    #pragma unroll
    for (int it = 0; it < 4; ++it) {
      const int c = it * 256 + tid;
      const int row = c >> 3, ckG = (c & 7) ^ (row & 7);
      gl_lds16(Bm + (size_t)(n0 + row) * HID + k0 + ckG * 16, &sB[c * 16]);
    }
    __syncthreads();
    #pragma unroll
    for (int kk = 0; kk < 2; ++kk) {
      i32x4 av[8], bv[4];
      const int ckW = kk * 4 + lq;
      #pragma unroll
      for (int i = 0; i < 8; ++i) av[i] = *frag(sA, wr + i * 16 + lm, ckW);
      #pragma unroll
      for (int j = 0; j < 4; ++j) bv[j] = *frag(sB, wc + j * 16 + lm, ckW);
      #pragma unroll
      for (int i = 0; i < 8; ++i)
        #pragma unroll
        for (int j = 0; j < 4; ++j)
          acc[i][j] = __builtin_amdgcn_mfma_i32_16x16x64_i8(av[i], bv[j], acc[i][j], 0, 0, 0);
    }
    __syncthreads();
  }
  const float s2 = scales[16 + e];
  float bb[4];
  #pragma unroll
  for (int j = 0; j < 4; ++j) bb[j] = b2[e * DIMS + n0 + wc + j * 16 + lm];
  #pragma unroll
  for (int i = 0; i < 8; ++i) {
    #pragma unroll
    for (int r = 0; r < 4; ++r) {
      const int row = m0 + wr + i * 16 + lq * 4 + r;
      const float rs = inv_sa[(size_t)e * T_TOK + row] * s2;
      const float g = gates[row * NE + e];
      #pragma unroll
      for (int j = 0; j < 4; ++j) {
        const int col = n0 + wc + j * 16 + lm;
        const float v = g * fmaf((float)acc[i][j][r], rs, bb[j]);
        if (use_atomic) atomicAdd(&((float*)dstv)[(size_t)row * DIMS + col], v);
        else __builtin_nontemporal_store(
                 (_Float16)v,
                 &((_Float16*)dstv)[((size_t)e * T_TOK + row) * DIMS + col]);
      }
    }
  }
}

// ---------- expert-sum reduce: f16 eout -> f32 out ----------
__global__ __launch_bounds__(256) void reduce_kernel(
    const f16x8* __restrict__ eout, float4* __restrict__ out) {
  const int i = blockIdx.x * 256 + threadIdx.x;  // over T*D/8 = 524288
  float s[8] = {};
  #pragma unroll
  for (int e = 0; e < NE; ++e) {
    f16x8 v = eout[(size_t)e * (T_TOK * DIMS / 8) + i];
    #pragma unroll
    for (int k = 0; k < 8; ++k) s[k] += (float)v[k];
  }
  float4 o0; o0.x = s[0]; o0.y = s[1]; o0.z = s[2]; o0.w = s[3];
  float4 o1; o1.x = s[4]; o1.y = s[5]; o1.z = s[6]; o1.w = s[7];
  out[i * 2]     = o0;
  out[i * 2 + 1] = o1;
}

// ---------- host orchestration ----------
extern "C" void kernel_launch(void* const* d_in, const int* in_sizes, int n_in,
                              void* d_out, int out_size, void* d_ws, size_t ws_size,
                              hipStream_t stream) {
  const float* x  = (const float*)d_in[0];
  const float* gw = (const float*)d_in[1];
  const float* gb = (const float*)d_in[2];
  const float* w1 = (const float*)d_in[3];
  const float* b1 = (const float*)d_in[4];
  const float* w2 = (const float*)d_in[5];
  const float* b2 = (const float*)d_in[6];
  float* outp = (float*)d_out;
  char* ws = (char*)d_ws;

  float* wsum   = (float*)(ws + 0);        // 17 floats
  float* scales = (float*)(ws + 256);      // 34 floats
  float* inv_sx = (float*)(ws + 4096);     // 4096 floats
  float* gates  = (float*)(ws + 20480);    // 32768 floats
  float* inv_sa = (float*)(ws + 151552);   // 32768 floats
  char*  qx     = ws + 282624;             // 4 MiB i8 [T][1024]
  char*  w1q    = ws + 4476928;            // 32 MiB i8
  char*  w2q    = ws + 38031360;           // 32 MiB i8
  char*  aqa    = ws + 71585792;           // 256 MiB: [E*T] rows of 8192 B
  char*  eout   = ws + 340021248;          // 64 MiB f16 [E][T][D] (optional)

  const bool has_eout = ws_size >= 340021248ull + 67108864ull;

  hipMemsetAsync(wsum, 0, 17 * sizeof(float), stream);
  wabs_sum_kernel<<<2048, 256, 0, stream>>>((const float4*)w1, 8388608, 20, wsum + 0);
  wabs_sum_kernel<<<2048, 256, 0, stream>>>((const float4*)w2, 8388608, 20, wsum + 8);
  wabs_sum_kernel<<<1,    256, 0, stream>>>((const float4*)gw, 2048,    30, wsum + 16);
  mkscales_kernel<<<1, 64, 0, stream>>>(wsum, scales);
  wquant_kernel<<<32768, 256, 0, stream>>>((const float4*)w1, (int*)w1q, 8388608, 20, scales + 8);
  wquant_kernel<<<32768, 256, 0, stream>>>((const float4*)w2, (int*)w2q, 8388608, 20, scales + 24);
  preprocess_kernel<<<4096, 256, 0, stream>>>(x, gw, gb, scales, (int*)qx, inv_sx, gates);

  gemm1_kernel<<<4096, 256, 0, stream>>>(qx, w1q, scales, inv_sx, b1, aqa);
  rowquant_kernel<<<32768, 256, 0, stream>>>(aqa, inv_sa);

  if (has_eout) {
    gemm2_kernel<<<1024, 256, 0, stream>>>(
        aqa, w2q, scales, inv_sa, b2, gates, eout, 0);
    reduce_kernel<<<2048, 256, 0, stream>>>((const f16x8*)eout, (float4*)outp);
  } else {
    hipMemsetAsync(outp, 0, (size_t)out_size * sizeof(float), stream);
    gemm2_kernel<<<1024, 256, 0, stream>>>(
        aqa, w2q, scales, inv_sa, b2, gates, outp, 1);
  }
}